// Round 4
// baseline (441.566 us; speedup 1.0000x reference)
//
#include <hip/hip_runtime.h>

// 8192x8192 fp32 -> per-8x8-block DCT-II, per-block inf-norm, int8 indices
// (stored as fp32). Output: [1024*1024*64 idx][1024*1024 biggest].
//
// R5: R3/R4 (shfl-butterfly) ran ~153 us vs ~90 us memory floor. Diagnosis:
// __shfl_xor lowers to ds_swizzle (LDS pipe) -> 54 DS ops/thread with 9
// dependent lgkmcnt waits per block, at ~4 waves/SIMD occupancy. Fixes:
//   - xor1/xor2 exchanges via DPP quad_perm (VALU pipe, no lgkmcnt):
//     ctrl 0xB1 = [1,0,3,2] (lane^1), 0x4E = [2,3,0,1] (lane^2).
//     Only the xor4 stage uses ds_swizzle (0x101F). 9 DS ops/thread total,
//     3 dependent DS waits per block (was 9).
//   - one 8x8 block per lane-octet per thread (was 2): live set ~40 VGPRs,
//     __launch_bounds__(256,8) caps at 64 -> 8 waves/SIMD for TLP.
// No LDS, no barriers. Stores: after the final butterfly each lane holds a
// full coefficient row -> 2 contiguous float4 (wave covers 2 KB/instr-pair).

#define IMG_H 8192
#define IMG_W 8192
#define NB1 (IMG_H / 8)
#define NB2 (IMG_W / 8)

// Orthonormal DCT-II matrix M[element][freq], fp32-exact constants.
__device__ __constant__ const float kM[8][8] = {
    { 0.35355339059327373f,  0.4903926402016152f,  0.4619397662556434f,
      0.4157348061512726f,  0.35355339059327373f,  0.2777851165098011f,
      0.1913417161825449f,  0.0975451610080642f },
    { 0.35355339059327373f,  0.4157348061512726f,  0.1913417161825449f,
     -0.0975451610080642f, -0.35355339059327373f, -0.4903926402016152f,
     -0.4619397662556434f, -0.2777851165098011f },
    { 0.35355339059327373f,  0.2777851165098011f, -0.1913417161825449f,
     -0.4903926402016152f, -0.35355339059327373f,  0.0975451610080642f,
      0.4619397662556434f,  0.4157348061512726f },
    { 0.35355339059327373f,  0.0975451610080642f, -0.4619397662556434f,
     -0.2777851165098011f,  0.35355339059327373f,  0.4157348061512726f,
     -0.1913417161825449f, -0.4903926402016152f },
    { 0.35355339059327373f, -0.0975451610080642f, -0.4619397662556434f,
      0.2777851165098011f,  0.35355339059327373f, -0.4157348061512726f,
     -0.1913417161825449f,  0.4903926402016152f },
    { 0.35355339059327373f, -0.2777851165098011f, -0.1913417161825449f,
      0.4903926402016152f, -0.35355339059327373f, -0.0975451610080642f,
      0.4619397662556434f, -0.4157348061512726f },
    { 0.35355339059327373f, -0.4157348061512726f,  0.1913417161825449f,
      0.0975451610080642f, -0.35355339059327373f,  0.4903926402016152f,
     -0.4619397662556434f,  0.2777851165098011f },
    { 0.35355339059327373f, -0.4903926402016152f,  0.4619397662556434f,
     -0.4157348061512726f,  0.35355339059327373f, -0.2777851165098011f,
      0.1913417161825449f, -0.0975451610080642f },
};

// Lane-exchange primitives. DPP quad_perm runs on the VALU pipe (no DS, no
// lgkmcnt); only lane^4 needs the LDS-pipe ds_swizzle.
template <int CTRL>
__device__ __forceinline__ float dpp_perm(float x) {
    const int xi = __float_as_int(x);
    return __int_as_float(
        __builtin_amdgcn_update_dpp(xi, xi, CTRL, 0xF, 0xF, false));
}
#define DPP_XOR1 0xB1  // quad_perm [1,0,3,2]
#define DPP_XOR2 0x4E  // quad_perm [2,3,0,1]

__device__ __forceinline__ float swz_xor4(float x) {
    // BitMode offset = (xor<<10)|(or<<5)|and = (4<<10)|0x1F = 0x101F
    return __int_as_float(
        __builtin_amdgcn_ds_swizzle(__float_as_int(x), 0x101F));
}

// 8x8 transpose distributed over 8 contiguous lanes (sub-index j), each
// lane holding 8 elements. Butterfly stage m swaps bit m between lane index
// and register index; element (j,g) <-> (j^m, g^m) where bits differ.
__device__ __forceinline__ void transpose8(float c[8], const int j) {
    // stage m=1 (DPP)
    {
        const bool hi = (j & 1) != 0;
#pragma unroll
        for (int g = 0; g < 8; g += 2) {
            const float a = c[g], b = c[g + 1];
            const float recv = dpp_perm<DPP_XOR1>(hi ? a : b);
            c[g]     = hi ? recv : a;
            c[g + 1] = hi ? b : recv;
        }
    }
    // stage m=2 (DPP)
    {
        const bool hi = (j & 2) != 0;
#pragma unroll
        for (int g = 0; g < 8; ++g) {
            if ((g & 2) == 0) {   // g in {0,1,4,5}
                const float a = c[g], b = c[g + 2];
                const float recv = dpp_perm<DPP_XOR2>(hi ? a : b);
                c[g]     = hi ? recv : a;
                c[g + 2] = hi ? b : recv;
            }
        }
    }
    // stage m=4 (ds_swizzle)
    {
        const bool hi = (j & 4) != 0;
#pragma unroll
        for (int g = 0; g < 4; ++g) {
            const float a = c[g], b = c[g + 4];
            const float recv = swz_xor4(hi ? a : b);
            c[g]     = hi ? recv : a;
            c[g + 4] = hi ? b : recv;
        }
    }
}

__global__ __launch_bounds__(256, 8) void dct_quant_kernel(
    const float* __restrict__ x,
    float* __restrict__ out_idx,   // NB1*NB2*64 floats
    float* __restrict__ out_big)   // NB1*NB2 floats
{
    const int t   = threadIdx.x;
    const int tb1 = blockIdx.x >> 7;    // 32-px band: 0..255
    const int tb2 = blockIdx.x & 127;   // 64-px column tile: 0..127

    const int j   = t & 7;          // row within block == lane sub-index
    const int bbc = (t >> 3) & 7;   // block col within tile (0..7)
    const int bbr = t >> 6;         // block row within tile (0..3)

    // Load row j of this lane-octet's block: 2x float4.
    const float* r0 = x + (size_t)(tb1 * 32 + bbr * 8 + j) * IMG_W
                        + tb2 * 64 + bbc * 8;
    const float4 a0 = ((const float4*)r0)[0];
    const float4 a1 = ((const float4*)r0)[1];
    float u[8] = {a0.x, a0.y, a0.z, a0.w, a1.x, a1.y, a1.z, a1.w};

    // Row transform: w[h] = sum_f u[f] * M[f][h]
    float w[8];
#pragma unroll
    for (int h = 0; h < 8; ++h) {
        float s = u[0] * kM[0][h];
#pragma unroll
        for (int f = 1; f < 8; ++f) s = fmaf(u[f], kM[f][h], s);
        w[h] = s;
    }

    // Transpose: lane j now holds column j of T1 (w[e] = T1[e][j]).
    transpose8(w, j);

    // Column transform: c[g] = sum_e M[e][g] * T1[e][j]  (-> C[g][j])
    float c[8];
    float big = 0.0f;
#pragma unroll
    for (int g = 0; g < 8; ++g) {
        float s = kM[0][g] * w[0];
#pragma unroll
        for (int e = 1; e < 8; ++e) s = fmaf(kM[e][g], w[e], s);
        c[g] = s;
        big = fmaxf(big, fabsf(s));
    }

    // Per-block inf-norm across the 8 column-owning lanes (group-uniform).
    big = fmaxf(big, dpp_perm<DPP_XOR1>(big));
    big = fmaxf(big, dpp_perm<DPP_XOR2>(big));
    big = fmaxf(big, swz_xor4(big));

    // Quantize (jnp.round = half-to-even -> rintf). Exact IEEE divide to
    // match the reference's 127/biggest.
    const float scale = 127.0f / big;
#pragma unroll
    for (int g = 0; g < 8; ++g) c[g] = rintf(c[g] * scale);

    // Transpose back: lane j now holds coefficient ROW j -> contiguous.
    transpose8(c, j);

    const int b1 = tb1 * 4 + bbr;
    const int b2 = tb2 * 8 + bbc;
    const size_t blk = (size_t)b1 * NB2 + b2;

    float* o = out_idx + blk * 64 + (size_t)j * 8;
    ((float4*)o)[0] = make_float4(c[0], c[1], c[2], c[3]);
    ((float4*)o)[1] = make_float4(c[4], c[5], c[6], c[7]);
    if (j == 0) out_big[blk] = big;
}

extern "C" void kernel_launch(void* const* d_in, const int* in_sizes, int n_in,
                              void* d_out, int out_size, void* d_ws, size_t ws_size,
                              hipStream_t stream) {
    const float* x = (const float*)d_in[0];
    // d_in[1] (dct matrix) is a fixed function of BLOCK=8, hardcoded
    // fp32-identically in the kernel.
    float* out = (float*)d_out;
    float* out_idx = out;
    float* out_big = out + (size_t)NB1 * NB2 * 64;

    dct_quant_kernel<<<32768, 256, 0, stream>>>(x, out_idx, out_big);
}